// Round 3
// baseline (457.072 us; speedup 1.0000x reference)
//
#include <hip/hip_runtime.h>

#define NUM_ENT 64
#define DIM_ENT 8
#define NHID    64
#define NEMB    256
#define BATCH   1024
#define NUM_REL 2016

typedef __attribute__((ext_vector_type(8))) short bf16x8;
typedef __attribute__((ext_vector_type(4))) float f32x4;

__device__ __forceinline__ unsigned short f2bf(float f) {
    union { float f; unsigned u; } v; v.f = f;
    unsigned r = v.u + 0x7FFF + ((v.u >> 16) & 1);   // RNE
    return (unsigned short)(r >> 16);
}

// ---------------------------------------------------------------------------
// Prep kernels: one-time (per launch) dtype/layout conversion into d_ws.
// ---------------------------------------------------------------------------

// ctx fp32 [1024,512] -> bf16 [1024,512] (entity rows stay 16B-granular)
__global__ void prep_ctx_kernel(const float* __restrict__ ctx,
                                unsigned short* __restrict__ ctxb) {
    const int id = blockIdx.x * 256 + threadIdx.x;        // 65536 threads x 8 elems
    const float4 a = ((const float4*)ctx)[id * 2];
    const float4 b = ((const float4*)ctx)[id * 2 + 1];
    bf16x8 v;
    v[0] = (short)f2bf(a.x); v[1] = (short)f2bf(a.y);
    v[2] = (short)f2bf(a.z); v[3] = (short)f2bf(a.w);
    v[4] = (short)f2bf(b.x); v[5] = (short)f2bf(b.y);
    v[6] = (short)f2bf(b.z); v[7] = (short)f2bf(b.w);
    *(bf16x8*)(ctxb + (size_t)id * 8) = v;
}

// Wfc fp32 [129024,256] -> bf16 in MFMA-B-fragment-linear order:
//   u16 index = ((g*2+kh)*16 + fid)*512 + l*8 + e
//   holds Wfc[g*64 + kh*32 + (l>>4)*8 + e][(fid>>1)*32 + (fid&1)*16 + (l&15)]
// so the main kernel's B-frag load is one coalesced dwordx4 per lane.
__global__ void prep_wfc_kernel(const float* __restrict__ Wfc,
                                unsigned short* __restrict__ wfcb) {
    const int id  = blockIdx.x * 256 + threadIdx.x;       // 4,128,768 lane-slots
    const int l   = id & 63;
    const int fid = (id >> 6) & 15;
    const int kh  = (id >> 10) & 1;
    const int g   = id >> 11;                             // relation 0..2015
    const int n   = (fid >> 1) * 32 + (fid & 1) * 16 + (l & 15);
    const int k0  = g * 64 + kh * 32 + ((l >> 4) << 3);
    const float* __restrict__ src = Wfc + (size_t)k0 * NEMB + n;
    bf16x8 v;
#pragma unroll
    for (int e = 0; e < 8; ++e) v[e] = (short)f2bf(src[(size_t)e * NEMB]);
    *(bf16x8*)(wfcb + (size_t)id * 8) = v;
}

// ---------------------------------------------------------------------------
// Fused main kernel (prepped path). 512 blocks, SPLITK=64 (slices of 32/31),
// XCD-bijective bid map: slice-sharers (8 mb) land on one XCD's L2.
// ---------------------------------------------------------------------------
template<bool ATOMIC>
__global__ __launch_bounds__(512, 4) void fused2_kernel(
    const unsigned short* __restrict__ ctxb,   // [1024,512] bf16
    const float*          __restrict__ Wrel,   // [16,64]
    const float*          __restrict__ brel,   // [64]
    const unsigned short* __restrict__ wfcb,   // frag-linear bf16
    float*                __restrict__ outp)   // ATOMIC: out[1024,256] ; else partial[64][1024,256]
{
    const int bid = blockIdx.x;
    const int mb  = (bid >> 3) & 7;                   // m-tile 0..7
    const int ks  = (bid & 7) + 8 * (bid >> 6);       // slice 0..63; ks%8 == bid%8 (XCD)
    const int start = (ks < 32) ? ks * 32 : 1024 + (ks - 32) * 31;
    const int cnt   = (ks < 32) ? 32 : 31;

    const int tid = threadIdx.x;
    const int w   = tid >> 6;
    const int l   = tid & 63;
    const int l15 = l & 15;
    const int kb  = l >> 4;

    __shared__ unsigned short h_lds[2][128 * NHID];   // 2 x 16 KiB, XOR-swizzled rows
    __shared__ int pair_i[32], pair_j[32];

    if (tid < cnt) {
        int rem = start + tid;
        int i = 0;
        while (rem >= (NUM_ENT - 1 - i)) { rem -= (NUM_ENT - 1 - i); ++i; }
        pair_i[tid] = i;
        pair_j[tid] = i + 1 + rem;
    }

    // W_rel B-frags (K padded 16->32) + bias
    bf16x8 bw[4];
    float  brl[4];
#pragma unroll
    for (int ns = 0; ns < 4; ++ns) {
        const int n = l15 + 16 * ns;
#pragma unroll
        for (int e = 0; e < 8; ++e) {
            const int k = kb * 8 + e;
            bw[ns][e] = (short)f2bf((k < 16) ? Wrel[k * NHID + n] : 0.f);
        }
        brl[ns] = brel[n];
    }

    __syncthreads();   // pair table ready

    f32x4 acc[8][2];
#pragma unroll
    for (int m = 0; m < 8; ++m)
#pragma unroll
        for (int n = 0; n < 2; ++n) acc[m][n] = (f32x4){0.f, 0.f, 0.f, 0.f};

    const int row_h = mb * 128 + w * 16 + l15;
    const unsigned short* __restrict__ ctx_row = ctxb + (size_t)row_h * (NUM_ENT * DIM_ENT);

    for (int r = 0; r < cnt; ++r) {
        const int g = start + r;
        unsigned short* __restrict__ hb = &h_lds[r & 1][0];

        // ---- issue B-frag loads early (independent of phase 1 / barrier) ----
        const unsigned short* __restrict__ wb =
            wfcb + (size_t)g * 16384 + (w * 2) * 512 + (size_t)l * 8;
        bf16x8 bb[2][2];
        bb[0][0] = *(const bf16x8*)(wb);
        bb[0][1] = *(const bf16x8*)(wb + 512);
        bb[1][0] = *(const bf16x8*)(wb + 16 * 512);
        bb[1][1] = *(const bf16x8*)(wb + 17 * 512);

        // ---- phase 1: h = relu(pairs @ W_rel + b_rel), 16 rows per wave ----
        bf16x8 ah = {0, 0, 0, 0, 0, 0, 0, 0};
        if (kb < 2) {
            const int ent = (kb == 0) ? pair_i[r] : pair_j[r];
            ah = *(const bf16x8*)(ctx_row + ent * DIM_ENT);
        }
#pragma unroll
        for (int ns = 0; ns < 4; ++ns) {
            f32x4 c = {0.f, 0.f, 0.f, 0.f};
            c = __builtin_amdgcn_mfma_f32_16x16x32_bf16(ah, bw[ns], c, 0, 0, 0);
#pragma unroll
            for (int reg = 0; reg < 4; ++reg) {
                float hv = c[reg] + brl[ns];
                hv = hv > 0.f ? hv : 0.f;
                const int rr = w * 16 + kb * 4 + reg;
                const int cc = l15 + 16 * ns;
                int byte = (rr * NHID + cc) * 2;
                byte ^= ((rr & 7) << 4);
                *(unsigned short*)((char*)hb + byte) = f2bf(hv);
            }
        }

        __syncthreads();   // h tile ready (double-buffered -> 1 barrier/iter)

        // ---- phase 2: acc += h[128,64] @ Wfc_slice ----
#pragma unroll
        for (int kh = 0; kh < 2; ++kh) {
#pragma unroll
            for (int m = 0; m < 8; ++m) {
                const int rr = m * 16 + l15;
                int byte = (rr * NHID + kh * 32 + kb * 8) * 2;
                byte ^= ((rr & 7) << 4);
                const bf16x8 aa = *(const bf16x8*)((const char*)hb + byte);
                acc[m][0] = __builtin_amdgcn_mfma_f32_16x16x32_bf16(aa, bb[kh][0], acc[m][0], 0, 0, 0);
                acc[m][1] = __builtin_amdgcn_mfma_f32_16x16x32_bf16(aa, bb[kh][1], acc[m][1], 0, 0, 0);
            }
        }
    }

    // ---- epilogue ----
    float* __restrict__ dst = ATOMIC ? outp : (outp + (size_t)ks * BATCH * NEMB);
#pragma unroll
    for (int m = 0; m < 8; ++m)
#pragma unroll
        for (int ns = 0; ns < 2; ++ns)
#pragma unroll
            for (int reg = 0; reg < 4; ++reg) {
                const int row = mb * 128 + m * 16 + kb * 4 + reg;
                const int col = w * 32 + ns * 16 + l15;
                if (ATOMIC) atomicAdd(&dst[(size_t)row * NEMB + col], acc[m][ns][reg]);
                else        dst[(size_t)row * NEMB + col] = acc[m][ns][reg];
            }
}

// partial[64][1024,256] -> out = relu(sum + bias)
__global__ void reduce_kernel(const float* __restrict__ part,
                              const float* __restrict__ bfc,
                              float* __restrict__ out) {
    const int i = blockIdx.x * 256 + threadIdx.x;     // float4 index, 65536 total
    float4 s = {0.f, 0.f, 0.f, 0.f};
    const float4* __restrict__ p = (const float4*)part + i;
#pragma unroll 16
    for (int ks = 0; ks < 64; ++ks) {
        const float4 v = p[(size_t)ks * (BATCH * NEMB / 4)];
        s.x += v.x; s.y += v.y; s.z += v.z; s.w += v.w;
    }
    const int c = (i * 4) & (NEMB - 1);
    s.x = fmaxf(s.x + bfc[c + 0], 0.f);
    s.y = fmaxf(s.y + bfc[c + 1], 0.f);
    s.z = fmaxf(s.z + bfc[c + 2], 0.f);
    s.w = fmaxf(s.w + bfc[c + 3], 0.f);
    ((float4*)out)[i] = s;
}

__global__ void bias_relu_kernel(float* __restrict__ out, const float* __restrict__ bfc) {
    const int i = blockIdx.x * 256 + threadIdx.x;
    float4 v = ((float4*)out)[i];
    const int c = (i * 4) & (NEMB - 1);
    v.x = fmaxf(v.x + bfc[c + 0], 0.f);
    v.y = fmaxf(v.y + bfc[c + 1], 0.f);
    v.z = fmaxf(v.z + bfc[c + 2], 0.f);
    v.w = fmaxf(v.w + bfc[c + 3], 0.f);
    ((float4*)out)[i] = v;
}

// ---------------------------------------------------------------------------
// Legacy fallback (round-2 kernel, known-pass) if d_ws is too small.
// ---------------------------------------------------------------------------
__global__ __launch_bounds__(512, 2) void fused_legacy_kernel(
    const float* __restrict__ ctx, const float* __restrict__ Wrel,
    const float* __restrict__ brel, const float* __restrict__ Wfc,
    float* __restrict__ out)
{
    const int bid = blockIdx.x;
    const int ks  = bid & 31;
    const int mb  = bid >> 5;
    const int tid = threadIdx.x;
    const int w   = tid >> 6;
    const int l   = tid & 63;
    const int l15 = l & 15;
    const int kb  = l >> 4;

    __shared__ unsigned short h_lds[2][128 * NHID];
    __shared__ int pair_i[63], pair_j[63];

    if (tid < 63) {
        int rem = ks * 63 + tid;
        int i = 0;
        while (rem >= (NUM_ENT - 1 - i)) { rem -= (NUM_ENT - 1 - i); ++i; }
        pair_i[tid] = i;
        pair_j[tid] = i + 1 + rem;
    }

    bf16x8 bw[4];
    float  brl[4];
#pragma unroll
    for (int ns = 0; ns < 4; ++ns) {
        const int n = l15 + 16 * ns;
#pragma unroll
        for (int e = 0; e < 8; ++e) {
            const int k = kb * 8 + e;
            bw[ns][e] = (short)f2bf((k < 16) ? Wrel[k * NHID + n] : 0.f);
        }
        brl[ns] = brel[n];
    }
    __syncthreads();

    f32x4 acc[8][2];
#pragma unroll
    for (int m = 0; m < 8; ++m)
#pragma unroll
        for (int n = 0; n < 2; ++n) acc[m][n] = (f32x4){0.f, 0.f, 0.f, 0.f};

    const int row_h = mb * 128 + w * 16 + l15;
    const float* __restrict__ ctx_row = ctx + (size_t)row_h * (NUM_ENT * DIM_ENT);

    for (int r = 0; r < 63; ++r) {
        unsigned short* __restrict__ hb = &h_lds[r & 1][0];
        bf16x8 ah = {0, 0, 0, 0, 0, 0, 0, 0};
        if (kb < 2) {
            const int ent = (kb == 0) ? pair_i[r] : pair_j[r];
            const float4 v0 = *(const float4*)(ctx_row + ent * DIM_ENT);
            const float4 v1 = *(const float4*)(ctx_row + ent * DIM_ENT + 4);
            ah[0] = (short)f2bf(v0.x); ah[1] = (short)f2bf(v0.y);
            ah[2] = (short)f2bf(v0.z); ah[3] = (short)f2bf(v0.w);
            ah[4] = (short)f2bf(v1.x); ah[5] = (short)f2bf(v1.y);
            ah[6] = (short)f2bf(v1.z); ah[7] = (short)f2bf(v1.w);
        }
#pragma unroll
        for (int ns = 0; ns < 4; ++ns) {
            f32x4 c = {0.f, 0.f, 0.f, 0.f};
            c = __builtin_amdgcn_mfma_f32_16x16x32_bf16(ah, bw[ns], c, 0, 0, 0);
#pragma unroll
            for (int reg = 0; reg < 4; ++reg) {
                float hv = c[reg] + brl[ns];
                hv = hv > 0.f ? hv : 0.f;
                const int rr = w * 16 + kb * 4 + reg;
                const int cc = l15 + 16 * ns;
                int byte = (rr * NHID + cc) * 2;
                byte ^= ((rr & 7) << 4);
                *(unsigned short*)((char*)hb + byte) = f2bf(hv);
            }
        }
        __syncthreads();

        const float* __restrict__ wf = Wfc + (size_t)(ks * 63 + r) * NHID * NEMB;
#pragma unroll
        for (int kh = 0; kh < 2; ++kh) {
            bf16x8 bb[2];
#pragma unroll
            for (int ns = 0; ns < 2; ++ns) {
                const int n = w * 32 + ns * 16 + l15;
                const float* __restrict__ col = wf + (size_t)(kh * 32 + kb * 8) * NEMB + n;
#pragma unroll
                for (int e = 0; e < 8; ++e) bb[ns][e] = (short)f2bf(col[(size_t)e * NEMB]);
            }
#pragma unroll
            for (int m = 0; m < 8; ++m) {
                const int rr = m * 16 + l15;
                int byte = (rr * NHID + kh * 32 + kb * 8) * 2;
                byte ^= ((rr & 7) << 4);
                const bf16x8 aa = *(const bf16x8*)((const char*)hb + byte);
                acc[m][0] = __builtin_amdgcn_mfma_f32_16x16x32_bf16(aa, bb[0], acc[m][0], 0, 0, 0);
                acc[m][1] = __builtin_amdgcn_mfma_f32_16x16x32_bf16(aa, bb[1], acc[m][1], 0, 0, 0);
            }
        }
    }
#pragma unroll
    for (int m = 0; m < 8; ++m)
#pragma unroll
        for (int ns = 0; ns < 2; ++ns)
#pragma unroll
            for (int reg = 0; reg < 4; ++reg) {
                const int row = mb * 128 + m * 16 + kb * 4 + reg;
                const int col = w * 32 + ns * 16 + l15;
                atomicAdd(&out[(size_t)row * NEMB + col], acc[m][ns][reg]);
            }
}

extern "C" void kernel_launch(void* const* d_in, const int* in_sizes, int n_in,
                              void* d_out, int out_size, void* d_ws, size_t ws_size,
                              hipStream_t stream) {
    const float* ctx  = (const float*)d_in[0];
    const float* Wrel = (const float*)d_in[1];
    const float* brel = (const float*)d_in[2];
    const float* Wfc  = (const float*)d_in[3];
    const float* bfc  = (const float*)d_in[4];
    float* out = (float*)d_out;

    const size_t CTXB = (size_t)BATCH * NUM_ENT * DIM_ENT * 2;        // 1 MiB
    const size_t WFCB = (size_t)NUM_REL * NHID * NEMB * 2;            // 63 MiB
    const size_t PART = (size_t)64 * BATCH * NEMB * 4;                // 64 MiB
    unsigned short* ctxb = (unsigned short*)d_ws;
    unsigned short* wfcb = (unsigned short*)((char*)d_ws + CTXB);
    float*          part = (float*)((char*)d_ws + CTXB + WFCB);

    if (ws_size >= CTXB + WFCB + PART) {
        prep_ctx_kernel<<<256, 256, 0, stream>>>(ctx, ctxb);
        prep_wfc_kernel<<<16128, 256, 0, stream>>>(Wfc, wfcb);
        fused2_kernel<false><<<512, 512, 0, stream>>>(ctxb, Wrel, brel, wfcb, part);
        reduce_kernel<<<256, 256, 0, stream>>>(part, bfc, out);
    } else if (ws_size >= CTXB + WFCB) {
        prep_ctx_kernel<<<256, 256, 0, stream>>>(ctx, ctxb);
        prep_wfc_kernel<<<16128, 256, 0, stream>>>(Wfc, wfcb);
        hipMemsetAsync(out, 0, (size_t)BATCH * NEMB * sizeof(float), stream);
        fused2_kernel<true><<<512, 512, 0, stream>>>(ctxb, Wrel, brel, wfcb, out);
        bias_relu_kernel<<<(BATCH * NEMB / 4) / 256, 256, 0, stream>>>(out, bfc);
    } else {
        hipMemsetAsync(out, 0, (size_t)BATCH * NEMB * sizeof(float), stream);
        fused_legacy_kernel<<<256, 512, 0, stream>>>(ctx, Wrel, brel, Wfc, out);
        bias_relu_kernel<<<(BATCH * NEMB / 4) / 256, 256, 0, stream>>>(out, bfc);
    }
}